// Round 12
// baseline (226.353 us; speedup 1.0000x reference)
//
#include <hip/hip_runtime.h>
#include <hip/hip_bf16.h>

#define BB 4
#define NN 4096
#define DD 128

typedef __attribute__((ext_vector_type(8))) short bf16x8;
typedef __attribute__((ext_vector_type(16))) float f32x16;

__device__ __forceinline__ unsigned short f2bf(float f) {
    unsigned u = __float_as_uint(f);
    return (unsigned short)((u + 0x7FFFu + ((u >> 16) & 1u)) >> 16);
}
__device__ __forceinline__ float bf2f(unsigned short s) {
    return __uint_as_float((unsigned)s << 16);
}
__device__ __forceinline__ unsigned pk2(float a, float b) {
    return (unsigned)f2bf(a) | ((unsigned)f2bf(b) << 16);
}

// ---------------------------------------------------------------------------
// Fragment-major layouts (shorts):
//   xbF: row-block rb = n>>5 (global over B*N), granule g = k>>3 (0..15):
//        addr = rb*4096 + g*256 + (n&31)*8 + (k&7)
//   vF:  per batch: d-block db = d>>5, m-granule g = m>>3 (0..511):
//        addr = b*524288 + db*131072 + g*256 + (d&31)*8 + (m&7)
//   wbF: j-block jb = j>>5, granule g = k>>3: jb*4096 + g*256 + (j&31)*8 + (k&7)
// ---------------------------------------------------------------------------

// prep: blocks 0..255 = x->bf16 frag-major (+transpose) + x2; blocks 256..263 = wt
__global__ __launch_bounds__(512) void prep_kernel(const float* __restrict__ x,
        const float* __restrict__ W, short* __restrict__ xbF,
        short* __restrict__ vF, short* __restrict__ wbF, float* __restrict__ x2) {
    if (blockIdx.x >= 256) {
        int t = (blockIdx.x - 256) * 512 + threadIdx.x;   // 0..4095
        int j = t >> 5, cq = t & 31;
        float4 v = *(const float4*)(W + j * 128 + cq * 4);
        uint2 pk; pk.x = pk2(v.x, v.y); pk.y = pk2(v.z, v.w);
        *(uint2*)(wbF + (j >> 5) * 4096 + (cq >> 1) * 256 + (j & 31) * 8 + (cq & 1) * 4) = pk;
        return;
    }
    __shared__ short Ls[64 * 136];
    int tid = threadIdx.x;
    int r = tid >> 3, cq = tid & 7;
    size_t rowg = (size_t)blockIdx.x * 64 + r;
    const float* xp = x + rowg * DD + cq * 16;
    short tmp[16];
    float s = 0.f;
    #pragma unroll
    for (int i = 0; i < 4; ++i) {
        float4 v = ((const float4*)xp)[i];
        unsigned short b0 = f2bf(v.x), b1 = f2bf(v.y), b2 = f2bf(v.z), b3 = f2bf(v.w);
        tmp[i*4+0] = (short)b0; tmp[i*4+1] = (short)b1;
        tmp[i*4+2] = (short)b2; tmp[i*4+3] = (short)b3;
        float f0 = bf2f(b0), f1 = bf2f(b1), f2 = bf2f(b2), f3 = bf2f(b3);
        s += f0*f0 + f1*f1 + f2*f2 + f3*f3;
    }
    #pragma unroll
    for (int c = 0; c < 2; ++c) {
        uint4 v = ((uint4*)tmp)[c];
        *(uint4*)(xbF + (rowg >> 5) * 4096 + (size_t)(cq * 2 + c) * 256 + (rowg & 31) * 8) = v;
        *(uint4*)(&Ls[r * 136 + cq * 16 + c * 8]) = v;
    }
    s += __shfl_xor(s, 1); s += __shfl_xor(s, 2); s += __shfl_xor(s, 4);
    if (cq == 0) x2[rowg] = s;
    __syncthreads();
    int d = tid & 127, q = tid >> 7;
    short arr[16];
    #pragma unroll
    for (int i = 0; i < 16; ++i) arr[i] = Ls[(q * 16 + i) * 136 + d];
    int blk = blockIdx.x, b = blk >> 6;
    int g0 = (blk & 63) * 8 + q * 2;
    size_t base = (size_t)b * 524288 + (size_t)(d >> 5) * 131072 + (size_t)(d & 31) * 8;
    *(uint4*)(vF + base + (size_t)g0 * 256)       = ((uint4*)arr)[0];
    *(uint4*)(vF + base + (size_t)(g0 + 1) * 256) = ((uint4*)arr)[1];
}

// ---------------------------------------------------------------------------
// attn: 512 blocks (b x ntile64 x mhalf2048) x 512 threads (8 waves), 2 blk/CU.
// Proven r5 loop body: QK wave owns 32m x 64n; Ws LDS exchange (swizzled);
// screen + skip; PV wave = (d-blk, n-half). Partial O merged via global atomics.
// ---------------------------------------------------------------------------
__global__ __launch_bounds__(512, 4) void attn_kernel(
        const short* __restrict__ xbF, const short* __restrict__ vF,
        const float* __restrict__ x2, const float* __restrict__ log_sigmas,
        float* __restrict__ O_ws) {
    __shared__ char smem[32832] __attribute__((aligned(128)));
    short* Ws = (short*)smem;                 // [64 n][512B m], granule ^= l5
    int* flags = (int*)(smem + 32768);        // 2 x 8 ints

    int tid = threadIdx.x, lane = tid & 63, w = tid >> 6;
    int l5 = lane & 31, hi = lane >> 5;

    int bid = (blockIdx.x & 7) * 64 + (blockIdx.x >> 3);   // XCD-bijective (512)
    int b = bid >> 7;
    int n0 = ((bid >> 1) & 63) * 64;
    int mh = bid & 1;

    const short* xf_b = xbF + (size_t)b * 524288;
    const short* vf_b = vF + (size_t)b * 524288;
    const float* x2b = x2 + (size_t)b * NN;

    float invd[4];
    #pragma unroll
    for (int h = 0; h < 4; ++h) {
        float sg = __expf(log_sigmas[h]);
        invd[h] = 1.0f / (2.0f * sg * sg + 1e-6f);
    }
    bool same = (invd[0] == invd[1]) && (invd[1] == invd[2]) && (invd[2] == invd[3]);
    float c0 = -invd[0];
    float invd_min = fminf(fminf(invd[0], invd[1]), fminf(invd[2], invd[3]));
    float thr = 30.0f / invd_min;

    // Q fragments (B-operand): rows n0+l5 (half A), n0+32+l5 (half B)
    bf16x8 qa[8], qb[8];
    {
        const short* qp = xf_b + (size_t)(n0 >> 5) * 4096;
        #pragma unroll
        for (int ck = 0; ck < 8; ++ck) {
            qa[ck] = *(const bf16x8*)(qp + (2 * ck + hi) * 256 + l5 * 8);
            qb[ck] = *(const bf16x8*)(qp + 4096 + (2 * ck + hi) * 256 + l5 * 8);
        }
    }
    float x2nA = x2b[n0 + l5], x2nB = x2b[n0 + 32 + l5];

    f32x16 O;
    #pragma unroll
    for (int i = 0; i < 16; ++i) O[i] = 0.f;

    int fb = 0;
    for (int t = 0; t < 8; ++t) {
        int m1 = mh * 2048 + t * 256;
        // K fragments (A-operand): rows m1 + w*32 + l5
        const short* kp = xf_b + (size_t)(mh * 64 + t * 8 + w) * 4096;
        bf16x8 kf[8];
        #pragma unroll
        for (int ck = 0; ck < 8; ++ck)
            kf[ck] = *(const bf16x8*)(kp + (2 * ck + hi) * 256 + l5 * 8);
        f32x16 SA, SB;
        #pragma unroll
        for (int i = 0; i < 16; ++i) { SA[i] = 0.f; SB[i] = 0.f; }
        #pragma unroll
        for (int ck = 0; ck < 8; ++ck) {
            SA = __builtin_amdgcn_mfma_f32_32x32x16_bf16(kf[ck], qa[ck], SA, 0, 0, 0);
            SB = __builtin_amdgcn_mfma_f32_32x32x16_bf16(kf[ck], qb[ck], SB, 0, 0, 0);
        }
        // dist^2: row m = m1+w*32+(8q+4hi+r), col n (A: n0+l5, B: n0+32+l5)
        float4 xm[4];
        #pragma unroll
        for (int q = 0; q < 4; ++q)
            xm[q] = *(const float4*)(x2b + m1 + w * 32 + 8 * q + 4 * hi);
        float dv[32];
        #pragma unroll
        for (int q = 0; q < 4; ++q)
            #pragma unroll
            for (int r = 0; r < 4; ++r) {
                float m2 = ((const float*)&xm[q])[r];
                dv[q * 4 + r]      = x2nA + m2 - 2.0f * SA[q * 4 + r];
                dv[16 + q * 4 + r] = x2nB + m2 - 2.0f * SB[q * 4 + r];
            }
        float pmin = dv[0];
        #pragma unroll
        for (int i = 1; i < 32; ++i) pmin = fminf(pmin, dv[i]);
        bool skipw = __all(pmin > thr);

        // Ws rows l5 (half A) and 32+l5 (half B); swizzle granule ^= l5
        if (skipw) {
            uint2 z; z.x = 0; z.y = 0;
            #pragma unroll
            for (int q = 0; q < 4; ++q) {
                *(uint2*)((char*)Ws + l5 * 512 + ((4 * w + q) ^ l5) * 16 + 8 * hi) = z;
                *(uint2*)((char*)Ws + (32 + l5) * 512 + ((4 * w + q) ^ l5) * 16 + 8 * hi) = z;
            }
        } else {
            #pragma unroll
            for (int h2 = 0; h2 < 2; ++h2) {
                int rowb = h2 * 32 + l5;
                #pragma unroll
                for (int q = 0; q < 4; ++q) {
                    float wv[4];
                    #pragma unroll
                    for (int r = 0; r < 4; ++r) {
                        float c = fmaxf(dv[h2 * 16 + q * 4 + r], 0.0f);
                        if (same) wv[r] = __expf(c * c0);
                        else wv[r] = 0.25f * (__expf(-c * invd[0]) + __expf(-c * invd[1]) +
                                              __expf(-c * invd[2]) + __expf(-c * invd[3]));
                    }
                    uint2 pk;
                    pk.x = pk2(wv[0], wv[1]);
                    pk.y = pk2(wv[2], wv[3]);
                    *(uint2*)((char*)Ws + rowb * 512 + ((4 * w + q) ^ l5) * 16 + 8 * hi) = pk;
                }
            }
        }
        if (lane == 0) flags[fb * 8 + w] = skipw ? 1 : 0;
        __syncthreads();
        const int4* fp = (const int4*)(flags + fb * 8);
        int4 f0 = fp[0], f1 = fp[1];
        bool allskip = (f0.x & f0.y & f0.z & f0.w & f1.x & f1.y & f1.z & f1.w) != 0;
        fb ^= 1;
        if (!allskip) {
            int db = w & 3, nh = w >> 2;
            const short* vp = vf_b + db * 131072 + (m1 >> 3) * 256;
            const char* wsr = (const char*)Ws + (nh * 32 + l5) * 512;
            #pragma unroll
            for (int ck = 0; ck < 16; ++ck) {
                bf16x8 af = *(const bf16x8*)(vp + (2 * ck + hi) * 256 + l5 * 8);
                bf16x8 bf = *(const bf16x8*)(wsr + (((2 * ck + hi) ^ l5) * 16));
                O = __builtin_amdgcn_mfma_f32_32x32x16_bf16(af, bf, O, 0, 0, 0);
            }
            __syncthreads();
        }
    }

    // merge partial O (wave = (db, nh); D rows = d, cols = n)
    {
        int db = w & 3, nh = w >> 2;
        float* Orow = O_ws + ((size_t)(b * NN + n0 + nh * 32 + l5)) * DD;
        #pragma unroll
        for (int i = 0; i < 16; ++i) {
            int d = db * 32 + (i & 3) + 8 * (i >> 2) + 4 * hi;
            atomicAdd(Orow + d, O[i]);
        }
    }
}

// ---------------------------------------------------------------------------
// epilogue: 256 blocks x 512 threads. O_ws -> proj MFMA -> ELU + res + LN.
// ---------------------------------------------------------------------------
__global__ __launch_bounds__(512) void epi_kernel(
        const float* __restrict__ O_ws, const short* __restrict__ wbF,
        const float* __restrict__ pb, const float* __restrict__ x,
        const float* __restrict__ gamma, const float* __restrict__ beta,
        float* __restrict__ out) {
    __shared__ float Plds[64 * 132];
    int tid = threadIdx.x, lane = tid & 63, w = tid >> 6;
    int l5 = lane & 31, hi = lane >> 5;
    int b = blockIdx.x >> 6, n0 = (blockIdx.x & 63) * 64;

    int jq = w & 3, nh2 = w >> 2;
    const float* orow = O_ws + ((size_t)(b * NN + n0 + nh2 * 32 + l5)) * DD;
    bf16x8 af[8];
    #pragma unroll
    for (int ck = 0; ck < 8; ++ck) {
        float4 a = *(const float4*)(orow + (2 * ck + hi) * 8);
        float4 c = *(const float4*)(orow + (2 * ck + hi) * 8 + 4);
        uint4 uu;
        uu.x = pk2(a.x, a.y); uu.y = pk2(a.z, a.w);
        uu.z = pk2(c.x, c.y); uu.w = pk2(c.z, c.w);
        af[ck] = *(bf16x8*)&uu;
    }
    f32x16 P;
    #pragma unroll
    for (int i = 0; i < 16; ++i) P[i] = 0.f;
    const short* wp = wbF + jq * 4096;
    #pragma unroll
    for (int ck = 0; ck < 8; ++ck) {
        bf16x8 bf = *(const bf16x8*)(wp + (2 * ck + hi) * 256 + l5 * 8);
        P = __builtin_amdgcn_mfma_f32_32x32x16_bf16(af[ck], bf, P, 0, 0, 0);
    }
    float pbj = pb[jq * 32 + l5];
    #pragma unroll
    for (int i = 0; i < 16; ++i) {
        int roff = (i & 3) + 8 * (i >> 2) + 4 * hi;
        Plds[(nh2 * 32 + roff) * 132 + jq * 32 + l5] = P[i] + pbj;
    }
    __syncthreads();

    int row = tid >> 3, part = tid & 7;
    const float* xr = x + ((size_t)b * NN + n0 + row) * DD + part * 16;
    float y[16];
    float sum = 0.f, ss = 0.f;
    #pragma unroll
    for (int c = 0; c < 4; ++c) {
        float4 pv = *(const float4*)(Plds + row * 132 + part * 16 + c * 4);
        float4 xv = *(const float4*)(xr + c * 4);
        #pragma unroll
        for (int k = 0; k < 4; ++k) {
            float p = ((const float*)&pv)[k];
            float e = (p > 0.f ? p : __expf(p) - 1.f) + ((const float*)&xv)[k];
            y[c * 4 + k] = e;
            sum += e; ss += e * e;
        }
    }
    sum += __shfl_xor(sum, 1); ss += __shfl_xor(ss, 1);
    sum += __shfl_xor(sum, 2); ss += __shfl_xor(ss, 2);
    sum += __shfl_xor(sum, 4); ss += __shfl_xor(ss, 4);
    float mu = sum * 0.0078125f;
    float var = fmaxf(ss * 0.0078125f - mu * mu, 0.f);
    float inv = rsqrtf(var + 1e-5f);
    float* op = out + ((size_t)b * NN + n0 + row) * DD + part * 16;
    #pragma unroll
    for (int c = 0; c < 4; ++c) {
        float4 gv = *(const float4*)(gamma + part * 16 + c * 4);
        float4 bv = *(const float4*)(beta + part * 16 + c * 4);
        float4 o;
        ((float*)&o)[0] = (y[c*4+0] - mu) * inv * ((const float*)&gv)[0] + ((const float*)&bv)[0];
        ((float*)&o)[1] = (y[c*4+1] - mu) * inv * ((const float*)&gv)[1] + ((const float*)&bv)[1];
        ((float*)&o)[2] = (y[c*4+2] - mu) * inv * ((const float*)&gv)[2] + ((const float*)&bv)[2];
        ((float*)&o)[3] = (y[c*4+3] - mu) * inv * ((const float*)&gv)[3] + ((const float*)&bv)[3];
        *(float4*)(op + c * 4) = o;
    }
}

extern "C" void kernel_launch(void* const* d_in, const int* in_sizes, int n_in,
                              void* d_out, int out_size, void* d_ws, size_t ws_size,
                              hipStream_t stream) {
    const float* x  = (const float*)d_in[0];
    const float* ls = (const float*)d_in[1];
    const float* pw = (const float*)d_in[2];
    const float* pb = (const float*)d_in[3];
    const float* g  = (const float*)d_in[4];
    const float* be = (const float*)d_in[5];
    float* out = (float*)d_out;

    char* ws = (char*)d_ws;
    short* xbF = (short*)ws;                                        // 4 MB
    short* vF  = (short*)(ws + (size_t)4 * 1024 * 1024);            // 4 MB
    float* x2  = (float*)(ws + (size_t)8 * 1024 * 1024);            // 64 KB
    short* wbF = (short*)(ws + (size_t)8 * 1024 * 1024 + 65536);    // 32 KB
    float* O_ws = (float*)(ws + (size_t)10 * 1024 * 1024);          // 8 MB

    hipMemsetAsync(O_ws, 0, (size_t)BB * NN * DD * sizeof(float), stream);
    prep_kernel<<<dim3(264), dim3(512), 0, stream>>>(x, pw, xbF, vF, wbF, x2);
    attn_kernel<<<dim3(512), dim3(512), 0, stream>>>(xbF, vF, x2, ls, O_ws);
    epi_kernel<<<dim3(256), dim3(512), 0, stream>>>(O_ws, wbF, pb, x, g, be, out);
}

// Round 13
// 205.001 us; speedup vs baseline: 1.1042x; 1.1042x over previous
//
#include <hip/hip_runtime.h>
#include <hip/hip_bf16.h>

#define BB 4
#define NN 4096
#define DD 128

typedef __attribute__((ext_vector_type(8))) short bf16x8;
typedef __attribute__((ext_vector_type(16))) float f32x16;

__device__ __forceinline__ unsigned short f2bf(float f) {
    unsigned u = __float_as_uint(f);
    return (unsigned short)((u + 0x7FFFu + ((u >> 16) & 1u)) >> 16);
}
__device__ __forceinline__ float bf2f(unsigned short s) {
    return __uint_as_float((unsigned)s << 16);
}
__device__ __forceinline__ unsigned pk2(float a, float b) {
    return (unsigned)f2bf(a) | ((unsigned)f2bf(b) << 16);
}

// ---------------------------------------------------------------------------
// Fragment-major layouts (shorts):
//   xbF: row-block rb = n>>5 (global over B*N), granule g = k>>3 (0..15):
//        addr = rb*4096 + g*256 + (n&31)*8 + (k&7)
//   vF:  per batch: d-block db = d>>5, m-granule g = m>>3 (0..511):
//        addr = b*524288 + db*131072 + g*256 + (d&31)*8 + (m&7)
//   wbF: j-block jb = j>>5, granule g = k>>3: jb*4096 + g*256 + (j&31)*8 + (k&7)
// ---------------------------------------------------------------------------

// prep: blocks 0..255 = x->bf16 frag-major (+transpose) + x2; blocks 256..263 = wt
__global__ __launch_bounds__(512) void prep_kernel(const float* __restrict__ x,
        const float* __restrict__ W, short* __restrict__ xbF,
        short* __restrict__ vF, short* __restrict__ wbF, float* __restrict__ x2) {
    if (blockIdx.x >= 256) {
        int t = (blockIdx.x - 256) * 512 + threadIdx.x;   // 0..4095
        int j = t >> 5, cq = t & 31;
        float4 v = *(const float4*)(W + j * 128 + cq * 4);
        uint2 pk; pk.x = pk2(v.x, v.y); pk.y = pk2(v.z, v.w);
        *(uint2*)(wbF + (j >> 5) * 4096 + (cq >> 1) * 256 + (j & 31) * 8 + (cq & 1) * 4) = pk;
        return;
    }
    __shared__ short Ls[64 * 136];
    int tid = threadIdx.x;
    int r = tid >> 3, cq = tid & 7;
    size_t rowg = (size_t)blockIdx.x * 64 + r;
    const float* xp = x + rowg * DD + cq * 16;
    short tmp[16];
    float s = 0.f;
    #pragma unroll
    for (int i = 0; i < 4; ++i) {
        float4 v = ((const float4*)xp)[i];
        unsigned short b0 = f2bf(v.x), b1 = f2bf(v.y), b2 = f2bf(v.z), b3 = f2bf(v.w);
        tmp[i*4+0] = (short)b0; tmp[i*4+1] = (short)b1;
        tmp[i*4+2] = (short)b2; tmp[i*4+3] = (short)b3;
        float f0 = bf2f(b0), f1 = bf2f(b1), f2 = bf2f(b2), f3 = bf2f(b3);
        s += f0*f0 + f1*f1 + f2*f2 + f3*f3;
    }
    #pragma unroll
    for (int c = 0; c < 2; ++c) {
        uint4 v = ((uint4*)tmp)[c];
        *(uint4*)(xbF + (rowg >> 5) * 4096 + (size_t)(cq * 2 + c) * 256 + (rowg & 31) * 8) = v;
        *(uint4*)(&Ls[r * 136 + cq * 16 + c * 8]) = v;
    }
    s += __shfl_xor(s, 1); s += __shfl_xor(s, 2); s += __shfl_xor(s, 4);
    if (cq == 0) x2[rowg] = s;
    __syncthreads();
    int d = tid & 127, q = tid >> 7;
    short arr[16];
    #pragma unroll
    for (int i = 0; i < 16; ++i) arr[i] = Ls[(q * 16 + i) * 136 + d];
    int blk = blockIdx.x, b = blk >> 6;
    int g0 = (blk & 63) * 8 + q * 2;
    size_t base = (size_t)b * 524288 + (size_t)(d >> 5) * 131072 + (size_t)(d & 31) * 8;
    *(uint4*)(vF + base + (size_t)g0 * 256)       = ((uint4*)arr)[0];
    *(uint4*)(vF + base + (size_t)(g0 + 1) * 256) = ((uint4*)arr)[1];
}

// ---------------------------------------------------------------------------
// attn: 512 blocks (b x ntile64 x mhalf2048) x 512 threads (8 waves).
// Launch bound (512,2) — the ONLY config with proven clean codegen (r5:
// VGPR=108, no spills). 2 blocks/CU co-resident at runtime (108<=128, LDS fits).
// Proven r5 loop body; partial O merged via global f32 atomics.
// ---------------------------------------------------------------------------
__global__ __launch_bounds__(512, 2) void attn_kernel(
        const short* __restrict__ xbF, const short* __restrict__ vF,
        const float* __restrict__ x2, const float* __restrict__ log_sigmas,
        float* __restrict__ O_ws) {
    __shared__ char smem[32832] __attribute__((aligned(128)));
    short* Ws = (short*)smem;                 // [64 n][512B m], granule ^= l5
    int* flags = (int*)(smem + 32768);        // 2 x 8 ints

    int tid = threadIdx.x, lane = tid & 63, w = tid >> 6;
    int l5 = lane & 31, hi = lane >> 5;

    int bid = (blockIdx.x & 7) * 64 + (blockIdx.x >> 3);   // XCD-bijective (512)
    int b = bid >> 7;
    int n0 = ((bid >> 1) & 63) * 64;
    int mh = bid & 1;

    const short* xf_b = xbF + (size_t)b * 524288;
    const short* vf_b = vF + (size_t)b * 524288;
    const float* x2b = x2 + (size_t)b * NN;

    float invd[4];
    #pragma unroll
    for (int h = 0; h < 4; ++h) {
        float sg = __expf(log_sigmas[h]);
        invd[h] = 1.0f / (2.0f * sg * sg + 1e-6f);
    }
    bool same = (invd[0] == invd[1]) && (invd[1] == invd[2]) && (invd[2] == invd[3]);
    float c0 = -invd[0];
    float invd_min = fminf(fminf(invd[0], invd[1]), fminf(invd[2], invd[3]));
    float thr = 30.0f / invd_min;

    // Q fragments (B-operand): rows n0+l5 (half A), n0+32+l5 (half B)
    bf16x8 qa[8], qb[8];
    {
        const short* qp = xf_b + (size_t)(n0 >> 5) * 4096;
        #pragma unroll
        for (int ck = 0; ck < 8; ++ck) {
            qa[ck] = *(const bf16x8*)(qp + (2 * ck + hi) * 256 + l5 * 8);
            qb[ck] = *(const bf16x8*)(qp + 4096 + (2 * ck + hi) * 256 + l5 * 8);
        }
    }
    float x2nA = x2b[n0 + l5], x2nB = x2b[n0 + 32 + l5];

    f32x16 O;
    #pragma unroll
    for (int i = 0; i < 16; ++i) O[i] = 0.f;

    int fb = 0;
    for (int t = 0; t < 8; ++t) {
        int m1 = mh * 2048 + t * 256;
        // K fragments (A-operand): rows m1 + w*32 + l5
        const short* kp = xf_b + (size_t)(mh * 64 + t * 8 + w) * 4096;
        bf16x8 kf[8];
        #pragma unroll
        for (int ck = 0; ck < 8; ++ck)
            kf[ck] = *(const bf16x8*)(kp + (2 * ck + hi) * 256 + l5 * 8);
        f32x16 SA, SB;
        #pragma unroll
        for (int i = 0; i < 16; ++i) { SA[i] = 0.f; SB[i] = 0.f; }
        #pragma unroll
        for (int ck = 0; ck < 8; ++ck) {
            SA = __builtin_amdgcn_mfma_f32_32x32x16_bf16(kf[ck], qa[ck], SA, 0, 0, 0);
            SB = __builtin_amdgcn_mfma_f32_32x32x16_bf16(kf[ck], qb[ck], SB, 0, 0, 0);
        }
        // dist^2: row m = m1+w*32+(8q+4hi+r), col n (A: n0+l5, B: n0+32+l5)
        float4 xm[4];
        #pragma unroll
        for (int q = 0; q < 4; ++q)
            xm[q] = *(const float4*)(x2b + m1 + w * 32 + 8 * q + 4 * hi);
        float dv[32];
        #pragma unroll
        for (int q = 0; q < 4; ++q)
            #pragma unroll
            for (int r = 0; r < 4; ++r) {
                float m2 = ((const float*)&xm[q])[r];
                dv[q * 4 + r]      = x2nA + m2 - 2.0f * SA[q * 4 + r];
                dv[16 + q * 4 + r] = x2nB + m2 - 2.0f * SB[q * 4 + r];
            }
        float pmin = dv[0];
        #pragma unroll
        for (int i = 1; i < 32; ++i) pmin = fminf(pmin, dv[i]);
        bool skipw = __all(pmin > thr);

        // Ws rows l5 (half A) and 32+l5 (half B); swizzle granule ^= l5
        if (skipw) {
            uint2 z; z.x = 0; z.y = 0;
            #pragma unroll
            for (int q = 0; q < 4; ++q) {
                *(uint2*)((char*)Ws + l5 * 512 + ((4 * w + q) ^ l5) * 16 + 8 * hi) = z;
                *(uint2*)((char*)Ws + (32 + l5) * 512 + ((4 * w + q) ^ l5) * 16 + 8 * hi) = z;
            }
        } else {
            #pragma unroll
            for (int h2 = 0; h2 < 2; ++h2) {
                int rowb = h2 * 32 + l5;
                #pragma unroll
                for (int q = 0; q < 4; ++q) {
                    float wv[4];
                    #pragma unroll
                    for (int r = 0; r < 4; ++r) {
                        float c = fmaxf(dv[h2 * 16 + q * 4 + r], 0.0f);
                        if (same) wv[r] = __expf(c * c0);
                        else wv[r] = 0.25f * (__expf(-c * invd[0]) + __expf(-c * invd[1]) +
                                              __expf(-c * invd[2]) + __expf(-c * invd[3]));
                    }
                    uint2 pk;
                    pk.x = pk2(wv[0], wv[1]);
                    pk.y = pk2(wv[2], wv[3]);
                    *(uint2*)((char*)Ws + rowb * 512 + ((4 * w + q) ^ l5) * 16 + 8 * hi) = pk;
                }
            }
        }
        if (lane == 0) flags[fb * 8 + w] = skipw ? 1 : 0;
        __syncthreads();
        const int4* fp = (const int4*)(flags + fb * 8);
        int4 f0 = fp[0], f1 = fp[1];
        bool allskip = (f0.x & f0.y & f0.z & f0.w & f1.x & f1.y & f1.z & f1.w) != 0;
        fb ^= 1;
        if (!allskip) {
            int db = w & 3, nh = w >> 2;
            const short* vp = vf_b + db * 131072 + (m1 >> 3) * 256;
            const char* wsr = (const char*)Ws + (nh * 32 + l5) * 512;
            #pragma unroll
            for (int ck = 0; ck < 16; ++ck) {
                bf16x8 af = *(const bf16x8*)(vp + (2 * ck + hi) * 256 + l5 * 8);
                bf16x8 bf = *(const bf16x8*)(wsr + (((2 * ck + hi) ^ l5) * 16));
                O = __builtin_amdgcn_mfma_f32_32x32x16_bf16(af, bf, O, 0, 0, 0);
            }
            __syncthreads();
        }
    }

    // merge partial O (wave = (db, nh); D rows = d, cols = n)
    {
        int db = w & 3, nh = w >> 2;
        float* Orow = O_ws + ((size_t)(b * NN + n0 + nh * 32 + l5)) * DD;
        #pragma unroll
        for (int i = 0; i < 16; ++i) {
            int d = db * 32 + (i & 3) + 8 * (i >> 2) + 4 * hi;
            atomicAdd(Orow + d, O[i]);
        }
    }
}

// ---------------------------------------------------------------------------
// epilogue: 256 blocks x 512 threads. O_ws -> proj MFMA -> ELU + res + LN.
// ---------------------------------------------------------------------------
__global__ __launch_bounds__(512) void epi_kernel(
        const float* __restrict__ O_ws, const short* __restrict__ wbF,
        const float* __restrict__ pb, const float* __restrict__ x,
        const float* __restrict__ gamma, const float* __restrict__ beta,
        float* __restrict__ out) {
    __shared__ float Plds[64 * 132];
    int tid = threadIdx.x, lane = tid & 63, w = tid >> 6;
    int l5 = lane & 31, hi = lane >> 5;
    int b = blockIdx.x >> 6, n0 = (blockIdx.x & 63) * 64;

    int jq = w & 3, nh2 = w >> 2;
    const float* orow = O_ws + ((size_t)(b * NN + n0 + nh2 * 32 + l5)) * DD;
    bf16x8 af[8];
    #pragma unroll
    for (int ck = 0; ck < 8; ++ck) {
        float4 a = *(const float4*)(orow + (2 * ck + hi) * 8);
        float4 c = *(const float4*)(orow + (2 * ck + hi) * 8 + 4);
        uint4 uu;
        uu.x = pk2(a.x, a.y); uu.y = pk2(a.z, a.w);
        uu.z = pk2(c.x, c.y); uu.w = pk2(c.z, c.w);
        af[ck] = *(bf16x8*)&uu;
    }
    f32x16 P;
    #pragma unroll
    for (int i = 0; i < 16; ++i) P[i] = 0.f;
    const short* wp = wbF + jq * 4096;
    #pragma unroll
    for (int ck = 0; ck < 8; ++ck) {
        bf16x8 bf = *(const bf16x8*)(wp + (2 * ck + hi) * 256 + l5 * 8);
        P = __builtin_amdgcn_mfma_f32_32x32x16_bf16(af[ck], bf, P, 0, 0, 0);
    }
    float pbj = pb[jq * 32 + l5];
    #pragma unroll
    for (int i = 0; i < 16; ++i) {
        int roff = (i & 3) + 8 * (i >> 2) + 4 * hi;
        Plds[(nh2 * 32 + roff) * 132 + jq * 32 + l5] = P[i] + pbj;
    }
    __syncthreads();

    int row = tid >> 3, part = tid & 7;
    const float* xr = x + ((size_t)b * NN + n0 + row) * DD + part * 16;
    float y[16];
    float sum = 0.f, ss = 0.f;
    #pragma unroll
    for (int c = 0; c < 4; ++c) {
        float4 pv = *(const float4*)(Plds + row * 132 + part * 16 + c * 4);
        float4 xv = *(const float4*)(xr + c * 4);
        #pragma unroll
        for (int k = 0; k < 4; ++k) {
            float p = ((const float*)&pv)[k];
            float e = (p > 0.f ? p : __expf(p) - 1.f) + ((const float*)&xv)[k];
            y[c * 4 + k] = e;
            sum += e; ss += e * e;
        }
    }
    sum += __shfl_xor(sum, 1); ss += __shfl_xor(ss, 1);
    sum += __shfl_xor(sum, 2); ss += __shfl_xor(ss, 2);
    sum += __shfl_xor(sum, 4); ss += __shfl_xor(ss, 4);
    float mu = sum * 0.0078125f;
    float var = fmaxf(ss * 0.0078125f - mu * mu, 0.f);
    float inv = rsqrtf(var + 1e-5f);
    float* op = out + ((size_t)b * NN + n0 + row) * DD + part * 16;
    #pragma unroll
    for (int c = 0; c < 4; ++c) {
        float4 gv = *(const float4*)(gamma + part * 16 + c * 4);
        float4 bv = *(const float4*)(beta + part * 16 + c * 4);
        float4 o;
        ((float*)&o)[0] = (y[c*4+0] - mu) * inv * ((const float*)&gv)[0] + ((const float*)&bv)[0];
        ((float*)&o)[1] = (y[c*4+1] - mu) * inv * ((const float*)&gv)[1] + ((const float*)&bv)[1];
        ((float*)&o)[2] = (y[c*4+2] - mu) * inv * ((const float*)&gv)[2] + ((const float*)&bv)[2];
        ((float*)&o)[3] = (y[c*4+3] - mu) * inv * ((const float*)&gv)[3] + ((const float*)&bv)[3];
        *(float4*)(op + c * 4) = o;
    }
}

extern "C" void kernel_launch(void* const* d_in, const int* in_sizes, int n_in,
                              void* d_out, int out_size, void* d_ws, size_t ws_size,
                              hipStream_t stream) {
    const float* x  = (const float*)d_in[0];
    const float* ls = (const float*)d_in[1];
    const float* pw = (const float*)d_in[2];
    const float* pb = (const float*)d_in[3];
    const float* g  = (const float*)d_in[4];
    const float* be = (const float*)d_in[5];
    float* out = (float*)d_out;

    char* ws = (char*)d_ws;
    short* xbF = (short*)ws;                                        // 4 MB
    short* vF  = (short*)(ws + (size_t)4 * 1024 * 1024);            // 4 MB
    float* x2  = (float*)(ws + (size_t)8 * 1024 * 1024);            // 64 KB
    short* wbF = (short*)(ws + (size_t)8 * 1024 * 1024 + 65536);    // 32 KB
    float* O_ws = (float*)(ws + (size_t)10 * 1024 * 1024);          // 8 MB

    hipMemsetAsync(O_ws, 0, (size_t)BB * NN * DD * sizeof(float), stream);
    prep_kernel<<<dim3(264), dim3(512), 0, stream>>>(x, pw, xbF, vF, wbF, x2);
    attn_kernel<<<dim3(512), dim3(512), 0, stream>>>(xbF, vF, x2, ls, O_ws);
    epi_kernel<<<dim3(256), dim3(512), 0, stream>>>(O_ws, wbF, pb, x, g, be, out);
}

// Round 14
// 61.701 us; speedup vs baseline: 3.6686x; 3.3225x over previous
//
#include <hip/hip_runtime.h>
#include <hip/hip_bf16.h>

#define BB 4
#define NN 4096
#define DD 128
#define OSTRIDE ((size_t)BB * NN * DD)

typedef __attribute__((ext_vector_type(8))) short bf16x8;
typedef __attribute__((ext_vector_type(16))) float f32x16;

__device__ __forceinline__ unsigned short f2bf(float f) {
    unsigned u = __float_as_uint(f);
    return (unsigned short)((u + 0x7FFFu + ((u >> 16) & 1u)) >> 16);
}
__device__ __forceinline__ float bf2f(unsigned short s) {
    return __uint_as_float((unsigned)s << 16);
}
__device__ __forceinline__ unsigned pk2(float a, float b) {
    return (unsigned)f2bf(a) | ((unsigned)f2bf(b) << 16);
}

// ---------------------------------------------------------------------------
// Fragment-major layouts (shorts):
//   xbF: row-block rb = n>>5 (global over B*N), granule g = k>>3 (0..15):
//        addr = rb*4096 + g*256 + (n&31)*8 + (k&7)
//   vF:  per batch: d-block db = d>>5, m-granule g = m>>3 (0..511):
//        addr = b*524288 + db*131072 + g*256 + (d&31)*8 + (m&7)
//   wbF: j-block jb = j>>5, granule g = k>>3: jb*4096 + g*256 + (j&31)*8 + (k&7)
// ---------------------------------------------------------------------------

// prep: blocks 0..255 = x->bf16 frag-major (+transpose) + x2; blocks 256..263 = wt
__global__ __launch_bounds__(512) void prep_kernel(const float* __restrict__ x,
        const float* __restrict__ W, short* __restrict__ xbF,
        short* __restrict__ vF, short* __restrict__ wbF, float* __restrict__ x2) {
    if (blockIdx.x >= 256) {
        int t = (blockIdx.x - 256) * 512 + threadIdx.x;   // 0..4095
        int j = t >> 5, cq = t & 31;
        float4 v = *(const float4*)(W + j * 128 + cq * 4);
        uint2 pk; pk.x = pk2(v.x, v.y); pk.y = pk2(v.z, v.w);
        *(uint2*)(wbF + (j >> 5) * 4096 + (cq >> 1) * 256 + (j & 31) * 8 + (cq & 1) * 4) = pk;
        return;
    }
    __shared__ short Ls[64 * 136];
    int tid = threadIdx.x;
    int r = tid >> 3, cq = tid & 7;
    size_t rowg = (size_t)blockIdx.x * 64 + r;
    const float* xp = x + rowg * DD + cq * 16;
    short tmp[16];
    float s = 0.f;
    #pragma unroll
    for (int i = 0; i < 4; ++i) {
        float4 v = ((const float4*)xp)[i];
        unsigned short b0 = f2bf(v.x), b1 = f2bf(v.y), b2 = f2bf(v.z), b3 = f2bf(v.w);
        tmp[i*4+0] = (short)b0; tmp[i*4+1] = (short)b1;
        tmp[i*4+2] = (short)b2; tmp[i*4+3] = (short)b3;
        float f0 = bf2f(b0), f1 = bf2f(b1), f2 = bf2f(b2), f3 = bf2f(b3);
        s += f0*f0 + f1*f1 + f2*f2 + f3*f3;
    }
    #pragma unroll
    for (int c = 0; c < 2; ++c) {
        uint4 v = ((uint4*)tmp)[c];
        *(uint4*)(xbF + (rowg >> 5) * 4096 + (size_t)(cq * 2 + c) * 256 + (rowg & 31) * 8) = v;
        *(uint4*)(&Ls[r * 136 + cq * 16 + c * 8]) = v;
    }
    s += __shfl_xor(s, 1); s += __shfl_xor(s, 2); s += __shfl_xor(s, 4);
    if (cq == 0) x2[rowg] = s;
    __syncthreads();
    int d = tid & 127, q = tid >> 7;
    short arr[16];
    #pragma unroll
    for (int i = 0; i < 16; ++i) arr[i] = Ls[(q * 16 + i) * 136 + d];
    int blk = blockIdx.x, b = blk >> 6;
    int g0 = (blk & 63) * 8 + q * 2;
    size_t base = (size_t)b * 524288 + (size_t)(d >> 5) * 131072 + (size_t)(d & 31) * 8;
    *(uint4*)(vF + base + (size_t)g0 * 256)       = ((uint4*)arr)[0];
    *(uint4*)(vF + base + (size_t)(g0 + 1) * 256) = ((uint4*)arr)[1];
}

// ---------------------------------------------------------------------------
// attn: 512 blocks (b x ntile64 x mhalf2048) x 512 threads (8 waves), (512,2).
// Proven r5 loop body. Partial O written with PLAIN stores to disjoint
// per-mhalf buffers (no atomics, no memset needed); epi merges.
// ---------------------------------------------------------------------------
__global__ __launch_bounds__(512, 2) void attn_kernel(
        const short* __restrict__ xbF, const short* __restrict__ vF,
        const float* __restrict__ x2, const float* __restrict__ log_sigmas,
        float* __restrict__ O_part) {
    __shared__ char smem[32832] __attribute__((aligned(128)));
    short* Ws = (short*)smem;                 // [64 n][512B m], granule ^= l5
    int* flags = (int*)(smem + 32768);        // 2 x 8 ints

    int tid = threadIdx.x, lane = tid & 63, w = tid >> 6;
    int l5 = lane & 31, hi = lane >> 5;

    int bid = (blockIdx.x & 7) * 64 + (blockIdx.x >> 3);   // XCD-bijective (512)
    int b = bid >> 7;
    int n0 = ((bid >> 1) & 63) * 64;
    int mh = bid & 1;

    const short* xf_b = xbF + (size_t)b * 524288;
    const short* vf_b = vF + (size_t)b * 524288;
    const float* x2b = x2 + (size_t)b * NN;

    float invd[4];
    #pragma unroll
    for (int h = 0; h < 4; ++h) {
        float sg = __expf(log_sigmas[h]);
        invd[h] = 1.0f / (2.0f * sg * sg + 1e-6f);
    }
    bool same = (invd[0] == invd[1]) && (invd[1] == invd[2]) && (invd[2] == invd[3]);
    float c0 = -invd[0];
    float invd_min = fminf(fminf(invd[0], invd[1]), fminf(invd[2], invd[3]));
    float thr = 30.0f / invd_min;

    // Q fragments (B-operand): rows n0+l5 (half A), n0+32+l5 (half B)
    bf16x8 qa[8], qb[8];
    {
        const short* qp = xf_b + (size_t)(n0 >> 5) * 4096;
        #pragma unroll
        for (int ck = 0; ck < 8; ++ck) {
            qa[ck] = *(const bf16x8*)(qp + (2 * ck + hi) * 256 + l5 * 8);
            qb[ck] = *(const bf16x8*)(qp + 4096 + (2 * ck + hi) * 256 + l5 * 8);
        }
    }
    float x2nA = x2b[n0 + l5], x2nB = x2b[n0 + 32 + l5];

    f32x16 O;
    #pragma unroll
    for (int i = 0; i < 16; ++i) O[i] = 0.f;

    int fb = 0;
    for (int t = 0; t < 8; ++t) {
        int m1 = mh * 2048 + t * 256;
        // K fragments (A-operand): rows m1 + w*32 + l5
        const short* kp = xf_b + (size_t)(mh * 64 + t * 8 + w) * 4096;
        bf16x8 kf[8];
        #pragma unroll
        for (int ck = 0; ck < 8; ++ck)
            kf[ck] = *(const bf16x8*)(kp + (2 * ck + hi) * 256 + l5 * 8);
        f32x16 SA, SB;
        #pragma unroll
        for (int i = 0; i < 16; ++i) { SA[i] = 0.f; SB[i] = 0.f; }
        #pragma unroll
        for (int ck = 0; ck < 8; ++ck) {
            SA = __builtin_amdgcn_mfma_f32_32x32x16_bf16(kf[ck], qa[ck], SA, 0, 0, 0);
            SB = __builtin_amdgcn_mfma_f32_32x32x16_bf16(kf[ck], qb[ck], SB, 0, 0, 0);
        }
        // dist^2: row m = m1+w*32+(8q+4hi+r), col n (A: n0+l5, B: n0+32+l5)
        float4 xm[4];
        #pragma unroll
        for (int q = 0; q < 4; ++q)
            xm[q] = *(const float4*)(x2b + m1 + w * 32 + 8 * q + 4 * hi);
        float dv[32];
        #pragma unroll
        for (int q = 0; q < 4; ++q)
            #pragma unroll
            for (int r = 0; r < 4; ++r) {
                float m2 = ((const float*)&xm[q])[r];
                dv[q * 4 + r]      = x2nA + m2 - 2.0f * SA[q * 4 + r];
                dv[16 + q * 4 + r] = x2nB + m2 - 2.0f * SB[q * 4 + r];
            }
        float pmin = dv[0];
        #pragma unroll
        for (int i = 1; i < 32; ++i) pmin = fminf(pmin, dv[i]);
        bool skipw = __all(pmin > thr);

        // Ws rows l5 (half A) and 32+l5 (half B); swizzle granule ^= l5
        if (skipw) {
            uint2 z; z.x = 0; z.y = 0;
            #pragma unroll
            for (int q = 0; q < 4; ++q) {
                *(uint2*)((char*)Ws + l5 * 512 + ((4 * w + q) ^ l5) * 16 + 8 * hi) = z;
                *(uint2*)((char*)Ws + (32 + l5) * 512 + ((4 * w + q) ^ l5) * 16 + 8 * hi) = z;
            }
        } else {
            #pragma unroll
            for (int h2 = 0; h2 < 2; ++h2) {
                int rowb = h2 * 32 + l5;
                #pragma unroll
                for (int q = 0; q < 4; ++q) {
                    float wv[4];
                    #pragma unroll
                    for (int r = 0; r < 4; ++r) {
                        float c = fmaxf(dv[h2 * 16 + q * 4 + r], 0.0f);
                        if (same) wv[r] = __expf(c * c0);
                        else wv[r] = 0.25f * (__expf(-c * invd[0]) + __expf(-c * invd[1]) +
                                              __expf(-c * invd[2]) + __expf(-c * invd[3]));
                    }
                    uint2 pk;
                    pk.x = pk2(wv[0], wv[1]);
                    pk.y = pk2(wv[2], wv[3]);
                    *(uint2*)((char*)Ws + rowb * 512 + ((4 * w + q) ^ l5) * 16 + 8 * hi) = pk;
                }
            }
        }
        if (lane == 0) flags[fb * 8 + w] = skipw ? 1 : 0;
        __syncthreads();
        const int4* fp = (const int4*)(flags + fb * 8);
        int4 f0 = fp[0], f1 = fp[1];
        bool allskip = (f0.x & f0.y & f0.z & f0.w & f1.x & f1.y & f1.z & f1.w) != 0;
        fb ^= 1;
        if (!allskip) {
            int db = w & 3, nh = w >> 2;
            const short* vp = vf_b + db * 131072 + (m1 >> 3) * 256;
            const char* wsr = (const char*)Ws + (nh * 32 + l5) * 512;
            #pragma unroll
            for (int ck = 0; ck < 16; ++ck) {
                bf16x8 af = *(const bf16x8*)(vp + (2 * ck + hi) * 256 + l5 * 8);
                bf16x8 bf = *(const bf16x8*)(wsr + (((2 * ck + hi) ^ l5) * 16));
                O = __builtin_amdgcn_mfma_f32_32x32x16_bf16(af, bf, O, 0, 0, 0);
            }
            __syncthreads();
        }
    }

    // write partial O with PLAIN stores (disjoint buffer per m-half)
    {
        int db = w & 3, nh = w >> 2;
        float* Orow = O_part + (size_t)mh * OSTRIDE +
                      ((size_t)(b * NN + n0 + nh * 32 + l5)) * DD;
        #pragma unroll
        for (int i = 0; i < 16; ++i) {
            int d = db * 32 + (i & 3) + 8 * (i >> 2) + 4 * hi;
            Orow[d] = O[i];
        }
    }
}

// ---------------------------------------------------------------------------
// epilogue: 256 blocks x 512 threads. O0+O1 -> proj MFMA -> ELU + res + LN.
// ---------------------------------------------------------------------------
__global__ __launch_bounds__(512) void epi_kernel(
        const float* __restrict__ O_part, const short* __restrict__ wbF,
        const float* __restrict__ pb, const float* __restrict__ x,
        const float* __restrict__ gamma, const float* __restrict__ beta,
        float* __restrict__ out) {
    __shared__ float Plds[64 * 132];
    int tid = threadIdx.x, lane = tid & 63, w = tid >> 6;
    int l5 = lane & 31, hi = lane >> 5;
    int b = blockIdx.x >> 6, n0 = (blockIdx.x & 63) * 64;

    int jq = w & 3, nh2 = w >> 2;
    const float* orow0 = O_part + ((size_t)(b * NN + n0 + nh2 * 32 + l5)) * DD;
    const float* orow1 = orow0 + OSTRIDE;
    bf16x8 af[8];
    #pragma unroll
    for (int ck = 0; ck < 8; ++ck) {
        int off = (2 * ck + hi) * 8;
        float4 a0 = *(const float4*)(orow0 + off);
        float4 c0v = *(const float4*)(orow0 + off + 4);
        float4 a1 = *(const float4*)(orow1 + off);
        float4 c1v = *(const float4*)(orow1 + off + 4);
        float4 a, c;
        a.x = a0.x + a1.x; a.y = a0.y + a1.y; a.z = a0.z + a1.z; a.w = a0.w + a1.w;
        c.x = c0v.x + c1v.x; c.y = c0v.y + c1v.y; c.z = c0v.z + c1v.z; c.w = c0v.w + c1v.w;
        uint4 uu;
        uu.x = pk2(a.x, a.y); uu.y = pk2(a.z, a.w);
        uu.z = pk2(c.x, c.y); uu.w = pk2(c.z, c.w);
        af[ck] = *(bf16x8*)&uu;
    }
    f32x16 P;
    #pragma unroll
    for (int i = 0; i < 16; ++i) P[i] = 0.f;
    const short* wp = wbF + jq * 4096;
    #pragma unroll
    for (int ck = 0; ck < 8; ++ck) {
        bf16x8 bf = *(const bf16x8*)(wp + (2 * ck + hi) * 256 + l5 * 8);
        P = __builtin_amdgcn_mfma_f32_32x32x16_bf16(af[ck], bf, P, 0, 0, 0);
    }
    float pbj = pb[jq * 32 + l5];
    #pragma unroll
    for (int i = 0; i < 16; ++i) {
        int roff = (i & 3) + 8 * (i >> 2) + 4 * hi;
        Plds[(nh2 * 32 + roff) * 132 + jq * 32 + l5] = P[i] + pbj;
    }
    __syncthreads();

    int row = tid >> 3, part = tid & 7;
    const float* xr = x + ((size_t)b * NN + n0 + row) * DD + part * 16;
    float y[16];
    float sum = 0.f, ss = 0.f;
    #pragma unroll
    for (int c = 0; c < 4; ++c) {
        float4 pv = *(const float4*)(Plds + row * 132 + part * 16 + c * 4);
        float4 xv = *(const float4*)(xr + c * 4);
        #pragma unroll
        for (int k = 0; k < 4; ++k) {
            float p = ((const float*)&pv)[k];
            float e = (p > 0.f ? p : __expf(p) - 1.f) + ((const float*)&xv)[k];
            y[c * 4 + k] = e;
            sum += e; ss += e * e;
        }
    }
    sum += __shfl_xor(sum, 1); ss += __shfl_xor(ss, 1);
    sum += __shfl_xor(sum, 2); ss += __shfl_xor(ss, 2);
    sum += __shfl_xor(sum, 4); ss += __shfl_xor(ss, 4);
    float mu = sum * 0.0078125f;
    float var = fmaxf(ss * 0.0078125f - mu * mu, 0.f);
    float inv = rsqrtf(var + 1e-5f);
    float* op = out + ((size_t)b * NN + n0 + row) * DD + part * 16;
    #pragma unroll
    for (int c = 0; c < 4; ++c) {
        float4 gv = *(const float4*)(gamma + part * 16 + c * 4);
        float4 bv = *(const float4*)(beta + part * 16 + c * 4);
        float4 o;
        ((float*)&o)[0] = (y[c*4+0] - mu) * inv * ((const float*)&gv)[0] + ((const float*)&bv)[0];
        ((float*)&o)[1] = (y[c*4+1] - mu) * inv * ((const float*)&gv)[1] + ((const float*)&bv)[1];
        ((float*)&o)[2] = (y[c*4+2] - mu) * inv * ((const float*)&gv)[2] + ((const float*)&bv)[2];
        ((float*)&o)[3] = (y[c*4+3] - mu) * inv * ((const float*)&gv)[3] + ((const float*)&bv)[3];
        *(float4*)(op + c * 4) = o;
    }
}

extern "C" void kernel_launch(void* const* d_in, const int* in_sizes, int n_in,
                              void* d_out, int out_size, void* d_ws, size_t ws_size,
                              hipStream_t stream) {
    const float* x  = (const float*)d_in[0];
    const float* ls = (const float*)d_in[1];
    const float* pw = (const float*)d_in[2];
    const float* pb = (const float*)d_in[3];
    const float* g  = (const float*)d_in[4];
    const float* be = (const float*)d_in[5];
    float* out = (float*)d_out;

    char* ws = (char*)d_ws;
    short* xbF = (short*)ws;                                        // 4 MB
    short* vF  = (short*)(ws + (size_t)4 * 1024 * 1024);            // 4 MB
    float* x2  = (float*)(ws + (size_t)8 * 1024 * 1024);            // 64 KB
    short* wbF = (short*)(ws + (size_t)8 * 1024 * 1024 + 65536);    // 32 KB
    float* O_part = (float*)(ws + (size_t)10 * 1024 * 1024);        // 2 x 8 MB

    prep_kernel<<<dim3(264), dim3(512), 0, stream>>>(x, pw, xbF, vF, wbF, x2);
    attn_kernel<<<dim3(512), dim3(512), 0, stream>>>(xbF, vF, x2, ls, O_part);
    epi_kernel<<<dim3(256), dim3(512), 0, stream>>>(O_part, wbF, pb, x, g, be, out);
}

// Round 15
// 51.507 us; speedup vs baseline: 4.3946x; 1.1979x over previous
//
#include <hip/hip_runtime.h>
#include <hip/hip_bf16.h>

#define BB 4
#define NN 4096
#define DD 128

typedef __attribute__((ext_vector_type(8))) short bf16x8;
typedef __attribute__((ext_vector_type(16))) float f32x16;

__device__ __forceinline__ unsigned short f2bf(float f) {
    unsigned u = __float_as_uint(f);
    return (unsigned short)((u + 0x7FFFu + ((u >> 16) & 1u)) >> 16);
}
__device__ __forceinline__ float bf2f(unsigned short s) {
    return __uint_as_float((unsigned)s << 16);
}
__device__ __forceinline__ unsigned pk2(float a, float b) {
    return (unsigned)f2bf(a) | ((unsigned)f2bf(b) << 16);
}

// ---------------------------------------------------------------------------
// Fragment-major layouts (shorts):
//   xbF: row-block rb = n>>5 (global over B*N), granule g = k>>3 (0..15):
//        addr = rb*4096 + g*256 + (n&31)*8 + (k&7)
//   vF:  per batch: d-block db = d>>5, m-granule g = m>>3 (0..511):
//        addr = b*524288 + db*131072 + g*256 + (d&31)*8 + (m&7)
//   wbF: j-block jb = j>>5, granule g = k>>3: jb*4096 + g*256 + (j&31)*8 + (k&7)
// ---------------------------------------------------------------------------

// prep: blocks 0..255 = x->bf16 frag-major (+transpose) + x2; blocks 256..263 = wt
__global__ __launch_bounds__(512) void prep_kernel(const float* __restrict__ x,
        const float* __restrict__ W, short* __restrict__ xbF,
        short* __restrict__ vF, short* __restrict__ wbF, float* __restrict__ x2) {
    if (blockIdx.x >= 256) {
        int t = (blockIdx.x - 256) * 512 + threadIdx.x;   // 0..4095
        int j = t >> 5, cq = t & 31;
        float4 v = *(const float4*)(W + j * 128 + cq * 4);
        uint2 pk; pk.x = pk2(v.x, v.y); pk.y = pk2(v.z, v.w);
        *(uint2*)(wbF + (j >> 5) * 4096 + (cq >> 1) * 256 + (j & 31) * 8 + (cq & 1) * 4) = pk;
        return;
    }
    __shared__ short Ls[64 * 136];
    int tid = threadIdx.x;
    int r = tid >> 3, cq = tid & 7;
    size_t rowg = (size_t)blockIdx.x * 64 + r;
    const float* xp = x + rowg * DD + cq * 16;
    short tmp[16];
    float s = 0.f;
    #pragma unroll
    for (int i = 0; i < 4; ++i) {
        float4 v = ((const float4*)xp)[i];
        unsigned short b0 = f2bf(v.x), b1 = f2bf(v.y), b2 = f2bf(v.z), b3 = f2bf(v.w);
        tmp[i*4+0] = (short)b0; tmp[i*4+1] = (short)b1;
        tmp[i*4+2] = (short)b2; tmp[i*4+3] = (short)b3;
        float f0 = bf2f(b0), f1 = bf2f(b1), f2 = bf2f(b2), f3 = bf2f(b3);
        s += f0*f0 + f1*f1 + f2*f2 + f3*f3;
    }
    #pragma unroll
    for (int c = 0; c < 2; ++c) {
        uint4 v = ((uint4*)tmp)[c];
        *(uint4*)(xbF + (rowg >> 5) * 4096 + (size_t)(cq * 2 + c) * 256 + (rowg & 31) * 8) = v;
        *(uint4*)(&Ls[r * 136 + cq * 16 + c * 8]) = v;
    }
    s += __shfl_xor(s, 1); s += __shfl_xor(s, 2); s += __shfl_xor(s, 4);
    if (cq == 0) x2[rowg] = s;
    __syncthreads();
    int d = tid & 127, q = tid >> 7;
    short arr[16];
    #pragma unroll
    for (int i = 0; i < 16; ++i) arr[i] = Ls[(q * 16 + i) * 136 + d];
    int blk = blockIdx.x, b = blk >> 6;
    int g0 = (blk & 63) * 8 + q * 2;
    size_t base = (size_t)b * 524288 + (size_t)(d >> 5) * 131072 + (size_t)(d & 31) * 8;
    *(uint4*)(vF + base + (size_t)g0 * 256)       = ((uint4*)arr)[0];
    *(uint4*)(vF + base + (size_t)(g0 + 1) * 256) = ((uint4*)arr)[1];
}

// ---------------------------------------------------------------------------
// pass A: screen. 512 blocks (b x ntile64 x mhalf) x 512 thr (8 waves).
// ZERO LDS, ZERO barriers. Wave w: full 64n (qa+qb), slices s = mh*64+t*8+w.
// Pure stream: load K frags -> 16 MFMA -> dist screen -> rare atomicOr bit.
// ---------------------------------------------------------------------------
__global__ __launch_bounds__(512, 2) void screen_kernel(
        const short* __restrict__ xbF, const float* __restrict__ x2,
        const float* __restrict__ log_sigmas, unsigned* __restrict__ mask) {
    int tid = threadIdx.x, lane = tid & 63, w = tid >> 6;
    int l5 = lane & 31, hi = lane >> 5;

    int bid = (blockIdx.x & 7) * 64 + (blockIdx.x >> 3);   // XCD-bijective
    int b = bid >> 7;
    int bn = bid >> 1;                 // (b, ntile64) 0..255
    int n0 = ((bid >> 1) & 63) * 64;
    int mh = bid & 1;

    const short* xf_b = xbF + (size_t)b * 524288;
    const float* x2b = x2 + (size_t)b * NN;

    float invd[4];
    #pragma unroll
    for (int h = 0; h < 4; ++h) {
        float sg = __expf(log_sigmas[h]);
        invd[h] = 1.0f / (2.0f * sg * sg + 1e-6f);
    }
    float invd_min = fminf(fminf(invd[0], invd[1]), fminf(invd[2], invd[3]));
    float thr = 30.0f / invd_min;

    bf16x8 qa[8], qb[8];
    {
        const short* qp = xf_b + (size_t)(n0 >> 5) * 4096;
        #pragma unroll
        for (int ck = 0; ck < 8; ++ck) {
            qa[ck] = *(const bf16x8*)(qp + (2 * ck + hi) * 256 + l5 * 8);
            qb[ck] = *(const bf16x8*)(qp + 4096 + (2 * ck + hi) * 256 + l5 * 8);
        }
    }
    float x2nA = x2b[n0 + l5], x2nB = x2b[n0 + 32 + l5];

    for (int t = 0; t < 8; ++t) {
        int s = mh * 64 + t * 8 + w;
        const short* kp = xf_b + (size_t)s * 4096;
        bf16x8 kf[8];
        #pragma unroll
        for (int ck = 0; ck < 8; ++ck)
            kf[ck] = *(const bf16x8*)(kp + (2 * ck + hi) * 256 + l5 * 8);
        f32x16 SA, SB;
        #pragma unroll
        for (int i = 0; i < 16; ++i) { SA[i] = 0.f; SB[i] = 0.f; }
        #pragma unroll
        for (int ck = 0; ck < 8; ++ck) {
            SA = __builtin_amdgcn_mfma_f32_32x32x16_bf16(kf[ck], qa[ck], SA, 0, 0, 0);
            SB = __builtin_amdgcn_mfma_f32_32x32x16_bf16(kf[ck], qb[ck], SB, 0, 0, 0);
        }
        float pmin = 1e30f;
        #pragma unroll
        for (int q = 0; q < 4; ++q) {
            float4 xm = *(const float4*)(x2b + s * 32 + 8 * q + 4 * hi);
            #pragma unroll
            for (int r = 0; r < 4; ++r) {
                float m2 = ((const float*)&xm)[r];
                pmin = fminf(pmin, x2nA + m2 - 2.0f * SA[q * 4 + r]);
                pmin = fminf(pmin, x2nB + m2 - 2.0f * SB[q * 4 + r]);
            }
        }
        if (!__all(pmin > thr) && lane == 0)
            atomicOr(&mask[bn * 4 + (s >> 5)], 1u << (s & 31));
    }
}

// ---------------------------------------------------------------------------
// pass B: live tiles + fused epilogue. 256 blocks (b x ntile64) x 512 thr.
// Read bitmap (~2 live slices) -> per-wave QK+W into LDS -> PV into regs ->
// O->LDS -> proj MFMA -> ELU + residual + LN -> out.
// ---------------------------------------------------------------------------
__global__ __launch_bounds__(512, 2) void live_kernel(
        const short* __restrict__ xbF, const short* __restrict__ vF,
        const float* __restrict__ x2, const unsigned* __restrict__ mask,
        const float* __restrict__ log_sigmas, const short* __restrict__ wbF,
        const float* __restrict__ pb, const float* __restrict__ x,
        const float* __restrict__ gamma, const float* __restrict__ beta,
        float* __restrict__ out) {
    __shared__ char smem[49664] __attribute__((aligned(128)));
    short* Wsb = (short*)smem;            // stage1: [8][64][48] shorts = 49152 B
    int* list = (int*)(smem + 49152);     // 128 ints
    float* O_lds = (float*)smem;          // stage2: [128][68] f32 = 34816 B
    float* Plds = (float*)smem;           // stage3: [64][132] f32 = 33792 B
    __shared__ int s_cnt;

    int tid = threadIdx.x, lane = tid & 63, w = tid >> 6;
    int l5 = lane & 31, hi = lane >> 5;
    int b = blockIdx.x >> 6, n0 = (blockIdx.x & 63) * 64;

    if (tid == 0) {
        int c = 0;
        #pragma unroll
        for (int wd = 0; wd < 4; ++wd) {
            unsigned mv = mask[blockIdx.x * 4 + wd];
            while (mv) { int bit = __ffs(mv) - 1; list[c++] = wd * 32 + bit; mv &= mv - 1; }
        }
        s_cnt = c;
    }
    __syncthreads();
    int nLive = s_cnt;

    const short* xf_b = xbF + (size_t)b * 524288;
    const short* vf_b = vF + (size_t)b * 524288;
    const float* x2b = x2 + (size_t)b * NN;

    float invd[4];
    #pragma unroll
    for (int h = 0; h < 4; ++h) {
        float sg = __expf(log_sigmas[h]);
        invd[h] = 1.0f / (2.0f * sg * sg + 1e-6f);
    }
    bool same = (invd[0] == invd[1]) && (invd[1] == invd[2]) && (invd[2] == invd[3]);
    float c0 = -invd[0];

    float x2nA = x2b[n0 + l5], x2nB = x2b[n0 + 32 + l5];
    int db = w & 3, nh = w >> 2;

    f32x16 O;
    #pragma unroll
    for (int i = 0; i < 16; ++i) O[i] = 0.f;

    for (int base = 0; base < nLive; base += 8) {
        int rem = nLive - base;
        int cnt = rem < 8 ? rem : 8;
        if (w < cnt) {
            int s = list[base + w];
            const short* qp = xf_b + (size_t)(n0 >> 5) * 4096;
            bf16x8 qa[8], qb[8];
            #pragma unroll
            for (int ck = 0; ck < 8; ++ck) {
                qa[ck] = *(const bf16x8*)(qp + (2 * ck + hi) * 256 + l5 * 8);
                qb[ck] = *(const bf16x8*)(qp + 4096 + (2 * ck + hi) * 256 + l5 * 8);
            }
            const short* kp = xf_b + (size_t)s * 4096;
            bf16x8 kf[8];
            #pragma unroll
            for (int ck = 0; ck < 8; ++ck)
                kf[ck] = *(const bf16x8*)(kp + (2 * ck + hi) * 256 + l5 * 8);
            f32x16 SA, SB;
            #pragma unroll
            for (int i = 0; i < 16; ++i) { SA[i] = 0.f; SB[i] = 0.f; }
            #pragma unroll
            for (int ck = 0; ck < 8; ++ck) {
                SA = __builtin_amdgcn_mfma_f32_32x32x16_bf16(kf[ck], qa[ck], SA, 0, 0, 0);
                SB = __builtin_amdgcn_mfma_f32_32x32x16_bf16(kf[ck], qb[ck], SB, 0, 0, 0);
            }
            float dv[32];
            #pragma unroll
            for (int q = 0; q < 4; ++q) {
                float4 xm = *(const float4*)(x2b + s * 32 + 8 * q + 4 * hi);
                #pragma unroll
                for (int r = 0; r < 4; ++r) {
                    float m2 = ((const float*)&xm)[r];
                    dv[q * 4 + r]      = x2nA + m2 - 2.0f * SA[q * 4 + r];
                    dv[16 + q * 4 + r] = x2nB + m2 - 2.0f * SB[q * 4 + r];
                }
            }
            #pragma unroll
            for (int h2 = 0; h2 < 2; ++h2) {
                int rowb = h2 * 32 + l5;
                #pragma unroll
                for (int q = 0; q < 4; ++q) {
                    float wv[4];
                    #pragma unroll
                    for (int r = 0; r < 4; ++r) {
                        float c = fmaxf(dv[h2 * 16 + q * 4 + r], 0.0f);
                        if (same) wv[r] = __expf(c * c0);
                        else wv[r] = 0.25f * (__expf(-c * invd[0]) + __expf(-c * invd[1]) +
                                              __expf(-c * invd[2]) + __expf(-c * invd[3]));
                    }
                    uint2 pk;
                    pk.x = pk2(wv[0], wv[1]);
                    pk.y = pk2(wv[2], wv[3]);
                    *(uint2*)(&Wsb[w * 3072 + rowb * 48 + 8 * q + 4 * hi]) = pk;
                }
            }
        }
        __syncthreads();
        for (int e2 = 0; e2 < cnt; ++e2) {
            int s = list[base + e2];
            const short* vp = vf_b + db * 131072 + (size_t)s * 1024;
            bf16x8 v0 = *(const bf16x8*)(vp + (size_t)hi * 256 + l5 * 8);
            bf16x8 v1 = *(const bf16x8*)(vp + (size_t)(2 + hi) * 256 + l5 * 8);
            bf16x8 wf0 = *(const bf16x8*)(&Wsb[e2 * 3072 + (nh * 32 + l5) * 48 + hi * 8]);
            bf16x8 wf1 = *(const bf16x8*)(&Wsb[e2 * 3072 + (nh * 32 + l5) * 48 + 16 + hi * 8]);
            O = __builtin_amdgcn_mfma_f32_32x32x16_bf16(v0, wf0, O, 0, 0, 0);
            O = __builtin_amdgcn_mfma_f32_32x32x16_bf16(v1, wf1, O, 0, 0, 0);
        }
        __syncthreads();
    }

    // stage 2: O -> O_lds (plain stores, wave-disjoint regions)
    #pragma unroll
    for (int i = 0; i < 16; ++i) {
        int droff = (i & 3) + 8 * (i >> 2) + 4 * hi;
        O_lds[(db * 32 + droff) * 68 + nh * 32 + l5] = O[i];
    }
    __syncthreads();

    // stage 3: proj MFMA (r7-proven)
    int jq = w & 3, nh2 = w >> 2;
    bf16x8 af[8];
    #pragma unroll
    for (int ck = 0; ck < 8; ++ck) {
        int dbase = ck * 16 + hi * 8;
        int nn = nh2 * 32 + l5;
        uint4 uu;
        uu.x = pk2(O_lds[(dbase + 0) * 68 + nn], O_lds[(dbase + 1) * 68 + nn]);
        uu.y = pk2(O_lds[(dbase + 2) * 68 + nn], O_lds[(dbase + 3) * 68 + nn]);
        uu.z = pk2(O_lds[(dbase + 4) * 68 + nn], O_lds[(dbase + 5) * 68 + nn]);
        uu.w = pk2(O_lds[(dbase + 6) * 68 + nn], O_lds[(dbase + 7) * 68 + nn]);
        af[ck] = *(bf16x8*)&uu;
    }
    f32x16 P;
    #pragma unroll
    for (int i = 0; i < 16; ++i) P[i] = 0.f;
    const short* wp = wbF + jq * 4096;
    #pragma unroll
    for (int ck = 0; ck < 8; ++ck) {
        bf16x8 bfr = *(const bf16x8*)(wp + (2 * ck + hi) * 256 + l5 * 8);
        P = __builtin_amdgcn_mfma_f32_32x32x16_bf16(af[ck], bfr, P, 0, 0, 0);
    }
    float pbj = pb[jq * 32 + l5];
    __syncthreads();   // O_lds reads complete before Plds overwrite
    #pragma unroll
    for (int i = 0; i < 16; ++i) {
        int roff = (i & 3) + 8 * (i >> 2) + 4 * hi;
        Plds[(nh2 * 32 + roff) * 132 + jq * 32 + l5] = P[i] + pbj;
    }
    __syncthreads();

    // stage 4: ELU + residual + LayerNorm (r14-proven)
    int row = tid >> 3, part = tid & 7;
    const float* xr = x + ((size_t)b * NN + n0 + row) * DD + part * 16;
    float y[16];
    float sum = 0.f, ss = 0.f;
    #pragma unroll
    for (int c = 0; c < 4; ++c) {
        float4 pv = *(const float4*)(Plds + row * 132 + part * 16 + c * 4);
        float4 xv = *(const float4*)(xr + c * 4);
        #pragma unroll
        for (int k = 0; k < 4; ++k) {
            float p = ((const float*)&pv)[k];
            float e = (p > 0.f ? p : __expf(p) - 1.f) + ((const float*)&xv)[k];
            y[c * 4 + k] = e;
            sum += e; ss += e * e;
        }
    }
    sum += __shfl_xor(sum, 1); ss += __shfl_xor(ss, 1);
    sum += __shfl_xor(sum, 2); ss += __shfl_xor(ss, 2);
    sum += __shfl_xor(sum, 4); ss += __shfl_xor(ss, 4);
    float mu = sum * 0.0078125f;
    float var = fmaxf(ss * 0.0078125f - mu * mu, 0.f);
    float inv = rsqrtf(var + 1e-5f);
    float* op = out + ((size_t)b * NN + n0 + row) * DD + part * 16;
    #pragma unroll
    for (int c = 0; c < 4; ++c) {
        float4 gv = *(const float4*)(gamma + part * 16 + c * 4);
        float4 bv = *(const float4*)(beta + part * 16 + c * 4);
        float4 o;
        ((float*)&o)[0] = (y[c*4+0] - mu) * inv * ((const float*)&gv)[0] + ((const float*)&bv)[0];
        ((float*)&o)[1] = (y[c*4+1] - mu) * inv * ((const float*)&gv)[1] + ((const float*)&bv)[1];
        ((float*)&o)[2] = (y[c*4+2] - mu) * inv * ((const float*)&gv)[2] + ((const float*)&bv)[2];
        ((float*)&o)[3] = (y[c*4+3] - mu) * inv * ((const float*)&gv)[3] + ((const float*)&bv)[3];
        *(float4*)(op + c * 4) = o;
    }
}

extern "C" void kernel_launch(void* const* d_in, const int* in_sizes, int n_in,
                              void* d_out, int out_size, void* d_ws, size_t ws_size,
                              hipStream_t stream) {
    const float* x  = (const float*)d_in[0];
    const float* ls = (const float*)d_in[1];
    const float* pw = (const float*)d_in[2];
    const float* pb = (const float*)d_in[3];
    const float* g  = (const float*)d_in[4];
    const float* be = (const float*)d_in[5];
    float* out = (float*)d_out;

    char* ws = (char*)d_ws;
    short* xbF = (short*)ws;                                        // 4 MB
    short* vF  = (short*)(ws + (size_t)4 * 1024 * 1024);            // 4 MB
    float* x2  = (float*)(ws + (size_t)8 * 1024 * 1024);            // 64 KB
    short* wbF = (short*)(ws + (size_t)8 * 1024 * 1024 + 65536);    // 32 KB
    unsigned* mask = (unsigned*)(ws + (size_t)8 * 1024 * 1024 + 131072);  // 4 KB

    hipMemsetAsync(mask, 0, 256 * 4 * sizeof(unsigned), stream);
    prep_kernel<<<dim3(264), dim3(512), 0, stream>>>(x, pw, xbF, vF, wbF, x2);
    screen_kernel<<<dim3(512), dim3(512), 0, stream>>>(xbF, x2, ls, mask);
    live_kernel<<<dim3(256), dim3(512), 0, stream>>>(
        xbF, vF, x2, mask, ls, wbF, pb, x, g, be, out);
}